// Round 11
// baseline (145.542 us; speedup 1.0000x reference)
//
#include <hip/hip_runtime.h>

constexpr int N_NODES = 100000;
constexpr int N_EDGES = 1600000;
constexpr int D = 32;
constexpr int NPB = 256;                            // nodes per bucket
constexpr int NBUK = (N_NODES + NPB - 1) / NPB;     // 391 buckets
constexpr int NCHUNK = 128;                         // edge chunks
constexpr int EPC = N_EDGES / NCHUNK;               // 12500 (exact)
constexpr int MAXPT = 32;                           // 32*256=8192 >= 4096 + many sigma
constexpr int TB = (NBUK + 63) / 64;                // 7 blocks for bucket-parallel prep

__device__ inline unsigned short f2bf(float f) {
    unsigned u = __float_as_uint(f);
    u += 0x7FFFu + ((u >> 16) & 1u);                // round-to-nearest-even
    return (unsigned short)(u >> 16);
}
__device__ inline float bf2f(unsigned short h) {
    return __uint_as_float(((unsigned)h) << 16);
}

// P0: node f32 -> bf16 table (64 B/row; ~6.4 MB, mostly L2-resident).
__global__ __launch_bounds__(256) void conv_kernel(const float4* __restrict__ in4,
                                                   ushort4* __restrict__ out4) {
    int i = blockIdx.x * 256 + threadIdx.x;         // 800000 exact
    float4 v = in4[i];
    out4[i] = make_ushort4(f2bf(v.x), f2bf(v.y), f2bf(v.z), f2bf(v.w));
}

// K1: per-chunk LDS histogram over buckets -> bgcnt[chunk][bucket]
// (chunk-major: hist writes coalesced + single-owner lines).
__global__ __launch_bounds__(256) void hist_kernel(const int4* __restrict__ dst4,
                                                   int* __restrict__ bgcnt) {
    __shared__ int cnt_s[512];
    const int k = blockIdx.x, t = threadIdx.x;
    cnt_s[t] = 0; cnt_s[t + 256] = 0;
    __syncthreads();
    const int base4 = k * (EPC / 4);
    for (int i = t; i < EPC / 4; i += 256) {
        int4 d = dst4[base4 + i];
        atomicAdd(&cnt_s[d.x >> 8], 1);
        atomicAdd(&cnt_s[d.y >> 8], 1);
        atomicAdd(&cnt_s[d.z >> 8], 1);
        atomicAdd(&cnt_s[d.w >> 8], 1);
    }
    __syncthreads();
    for (int b = t; b < NBUK; b += 256) bgcnt[k * NBUK + b] = cnt_s[b];
}

// K2a: per-bucket totals. lane = bucket (coalesced across lanes for each k).
__global__ __launch_bounds__(64) void tot_kernel(const int* __restrict__ bgcnt,
                                                 int* __restrict__ tot) {
    const int b = blockIdx.x * 64 + threadIdx.x;
    if (b >= NBUK) return;
    int s = 0;
    #pragma unroll 8
    for (int k = 0; k < NCHUNK; ++k) s += bgcnt[k * NBUK + b];
    tot[b] = s;
}

// K2b: exclusive scan of the 391 bucket totals -> boff.
__global__ __launch_bounds__(512) void scan_kernel(const int* __restrict__ tot,
                                                   int* __restrict__ boff) {
    __shared__ int part[512];
    const int t = threadIdx.x;
    int v = (t < NBUK) ? tot[t] : 0;
    part[t] = v;
    __syncthreads();
    for (int d = 1; d < 512; d <<= 1) {
        int u = (t >= d) ? part[t - d] : 0;
        __syncthreads();
        part[t] += u;
        __syncthreads();
    }
    if (t < NBUK) boff[t] = part[t] - v;
}

// K2c: per-(chunk,bucket) stripe starts. lane = bucket; serial carry over k
// with coalesced loads/stores (independent loads hide latency).
__global__ __launch_bounds__(64) void gstart_kernel(const int* __restrict__ bgcnt,
                                                    const int* __restrict__ boff,
                                                    int* __restrict__ gstart) {
    const int b = blockIdx.x * 64 + threadIdx.x;
    if (b >= NBUK) return;
    int carry = boff[b];
    #pragma unroll 8
    for (int k = 0; k < NCHUNK; ++k) {
        gstart[k * NBUK + b] = carry;
        carry += bgcnt[k * NBUK + b];
    }
}

// K3: scatter packed records (e | local<<21) into bucket-major order.
// Each (bucket,chunk) stripe is contiguous, written by exactly one block.
__global__ __launch_bounds__(256) void scatter_kernel(const int4* __restrict__ dst4,
                                                      const int* __restrict__ gstart,
                                                      int* __restrict__ records) {
    __shared__ int cur_s[512];
    const int k = blockIdx.x, t = threadIdx.x;
    for (int b = t; b < 512; b += 256)
        cur_s[b] = (b < NBUK) ? gstart[k * NBUK + b] : 0;
    __syncthreads();
    const int base4 = k * (EPC / 4);
    for (int i = t; i < EPC / 4; i += 256) {
        int4 d = dst4[base4 + i];
        const int e = (base4 + i) * 4;
        int p;
        p = atomicAdd(&cur_s[d.x >> 8], 1); records[p] = e       | ((d.x & 255) << 21);
        p = atomicAdd(&cur_s[d.y >> 8], 1); records[p] = (e + 1) | ((d.y & 255) << 21);
        p = atomicAdd(&cur_s[d.z >> 8], 1); records[p] = (e + 2) | ((d.z & 255) << 21);
        p = atomicAdd(&cur_s[d.w >> 8], 1); records[p] = (e + 3) | ((d.w & 255) << 21);
    }
}

// K4: one block per bucket. Register-buffer the records, LDS hist+scan of the
// 256 local nodes -> offcnt, then emit node-sorted CSR as eidsrc = (e, src[e]).
__global__ __launch_bounds__(256) void finalize_kernel(const int* __restrict__ records,
                                                       const int* __restrict__ src,
                                                       const int* __restrict__ boff,
                                                       int2* __restrict__ offcnt,
                                                       int2* __restrict__ eidsrc) {
    __shared__ int cnt_s[NPB];
    __shared__ int cur_s[NPB];
    __shared__ int wsum_s[4];
    const int b = blockIdx.x, t = threadIdx.x;
    const int s0 = boff[b];
    const int tot = ((b + 1 < NBUK) ? boff[b + 1] : N_EDGES) - s0;
    cnt_s[t] = 0;
    __syncthreads();

    int held[MAXPT];
    #pragma unroll
    for (int r = 0; r < MAXPT; ++r) {
        const int i = t + r * 256;
        held[r] = (i < tot) ? records[s0 + i] : -1;
        if (held[r] >= 0) atomicAdd(&cnt_s[held[r] >> 21], 1);
    }
    __syncthreads();

    const int lane = t & 63, w = t >> 6;
    const int v = cnt_s[t];
    int incl = v;
    #pragma unroll
    for (int dd = 1; dd < 64; dd <<= 1) {
        int u = __shfl_up(incl, dd, 64);
        if (lane >= dd) incl += u;
    }
    if (lane == 63) wsum_s[w] = incl;
    __syncthreads();
    int wo = 0;
    for (int ww = 0; ww < w; ++ww) wo += wsum_s[ww];
    const int excl = s0 + wo + incl - v;
    cur_s[t] = excl;
    const int gn = b * NPB + t;
    if (gn < N_NODES) offcnt[gn] = make_int2(excl, v);
    __syncthreads();

    #pragma unroll
    for (int r = 0; r < MAXPT; ++r) {
        if (held[r] >= 0) {
            const int e = held[r] & 0x1FFFFF;
            const int pos = atomicAdd(&cur_s[held[r] >> 21], 1);
            eidsrc[pos] = make_int2(e, src[e]);     // src gather: L2-hot, hidden
        }
    }
}

// K5: per-node gather-sum + eps-update + 32x32 linear. 32 lanes per node,
// single coalesced int2 prefetch (e,s) per 32 edges, 16-wide batches.
// Edge rows f32 (random, L3); node rows bf16 (random, mostly L2).
__global__ __launch_bounds__(256) void gather_node_kernel(
    const float* __restrict__ node, const unsigned short* __restrict__ nodeb,
    const float* __restrict__ edge, const int2* __restrict__ eidsrc,
    const int2* __restrict__ offcnt,
    const float* __restrict__ W, const float* __restrict__ bvec,
    const float* __restrict__ eps, float* __restrict__ out)
{
    __shared__ float Ws[D][D + 1];
    __shared__ float bs[D];
    const int t = threadIdx.x;
    for (int i = t; i < D * D; i += 256) Ws[i >> 5][i & 31] = W[i];
    if (t < D) bs[t] = bvec[t];
    __syncthreads();

    const int g = t >> 5;
    const int o = t & 31;
    const int nodeid = blockIdx.x * 8 + g;          // 12500*8 exact

    const int2 oc = offcnt[nodeid];
    const int start = oc.x;
    const int n = oc.y;
    float acc = 0.0f;

    for (int c = 0; c < n; c += 32) {
        const int m = min(32, n - c);
        int e_l = 0, s_l = 0;
        if (o < m) {
            const int2 es = eidsrc[start + c + o];  // ONE coalesced dependent load
            e_l = es.x; s_l = es.y;
        }
        for (int j = 0; j < m; j += 16) {
            float ev[16], nv[16];
            #pragma unroll
            for (int u = 0; u < 16; ++u) {
                const int jj = j + u;
                const int ls = (jj < m) ? jj : (m - 1);   // clamp: dup row, L1-hit
                const int e = __shfl(e_l, ls, 32);
                const int s = __shfl(s_l, ls, 32);
                ev[u] = edge[(long long)e * D + o];               // 128B random
                nv[u] = bf2f(nodeb[(long long)s * D + o]);        // 64B random, L2
            }
            #pragma unroll
            for (int u = 0; u < 16; ++u)
                if (j + u < m) acc += fmaxf(ev[u] + nv[u], 0.0f);
        }
    }

    const float scale = 1.0f + eps[0];
    const float h = scale * node[(long long)nodeid * D + o] + acc;  // self term f32

    float r = bs[o];
    #pragma unroll
    for (int kk = 0; kk < D; ++kk) r += __shfl(h, kk, 32) * Ws[o][kk];
    out[(long long)nodeid * D + o] = r;
}

extern "C" void kernel_launch(void* const* d_in, const int* in_sizes, int n_in,
                              void* d_out, int out_size, void* d_ws, size_t ws_size,
                              hipStream_t stream) {
    const float* node = (const float*)d_in[0];
    const float* edge = (const float*)d_in[1];
    const int*   src  = (const int*)d_in[2];
    const int*   dst  = (const int*)d_in[3];
    const float* W    = (const float*)d_in[4];
    const float* b    = (const float*)d_in[5];
    const float* eps  = (const float*)d_in[6];
    float* out = (float*)d_out;

    // Workspace: eidsrc int2[E] | offcnt int2[N] | records[E] |
    //            bgcnt[NCHUNK*NBUK] | gstart[NCHUNK*NBUK] | boff[NBUK] |
    //            tot[NBUK] | nodeb ushort[N*D]        (~27 MB total)
    int2* eidsrc = (int2*)d_ws;
    int2* offcnt = eidsrc + N_EDGES;
    int*  records = (int*)(offcnt + N_NODES);
    int*  bgcnt   = records + N_EDGES;
    int*  gstart  = bgcnt + NCHUNK * NBUK;
    int*  boff    = gstart + NCHUNK * NBUK;
    int*  tot     = boff + NBUK;
    unsigned short* nodeb = (unsigned short*)(tot + NBUK);

    conv_kernel<<<(N_NODES * D / 4) / 256, 256, 0, stream>>>(
        (const float4*)node, (ushort4*)nodeb);
    hist_kernel<<<NCHUNK, 256, 0, stream>>>((const int4*)dst, bgcnt);
    tot_kernel<<<TB, 64, 0, stream>>>(bgcnt, tot);
    scan_kernel<<<1, 512, 0, stream>>>(tot, boff);
    gstart_kernel<<<TB, 64, 0, stream>>>(bgcnt, boff, gstart);
    scatter_kernel<<<NCHUNK, 256, 0, stream>>>((const int4*)dst, gstart, records);
    finalize_kernel<<<NBUK, 256, 0, stream>>>(records, src, boff, offcnt, eidsrc);

    gather_node_kernel<<<N_NODES / 8, 256, 0, stream>>>(node, nodeb, edge, eidsrc,
                                                        offcnt, W, b, eps, out);
}